// Round 11
// baseline (149.364 us; speedup 1.0000x reference)
//
#include <hip/hip_runtime.h>
#include <hip/hip_bf16.h>

// Single persistent kernel, 4 barriers (measured-best structure, R6/R9 = 49us
// kernel; 2-barrier variants measured WORSE: R10=55us). This round's isolated
// experiment: CODE-SIZE DIET (roll the replicated table-build loops) to test
// the per-launch cold-icache hypothesis, plus static keys-row prefetch.
// Structure (validated R1-R10): looper == sigmoid(3.0) exactly -> exactly two
// long_conv applications; lc_* inputs unused. Phases:
//   A: key1[3][1024] = sigmoid(sampled stride-2 conv of 2x-1)  [distributed]
//   bar1
//   B: logit1[100] = keys @ key1, one block per row (keys row pre-loaded)
//   bar2
//   C: softmax -> kern1 (LDS) -> w_eff (LDS)            [REPLICATED, all blocks]
//   D: key2 via w_eff (composite conv(convT(.,kern1)))          [distributed]
//   bar3
//   E: logit2[100]
//   bar4
//   F: softmax -> kern2 (LDS) -> composite stride-4 13x13 convT weights
//      W/Wy/Wx/Wxy in LDS (ROLLED loops)                [REPLICATED, all blocks]
//   G: out = sigmoid(composite convT at (i*4093/128, j*4093/128))
// Ledger: agent acquire/release fences forbidden (buffer_inv/wbl2, R4);
// cross-block data sc1 relaxed-agent only; barrier mechanics irrelevant
// (R9 two-level == R6 single); no dynamic-indexed register arrays (R7 spill).
// Deadlock safety: 128 blocks x 256 thr, launch_bounds(256,1), 10.5KB LDS.

#define GRID 128

#define LD1(p)     __hip_atomic_load((p), __ATOMIC_RELAXED, __HIP_MEMORY_SCOPE_AGENT)
#define ST1(p, v)  __hip_atomic_store((p), (v), __ATOMIC_RELAXED, __HIP_MEMORY_SCOPE_AGENT)

__device__ __forceinline__ float sigmoidf_(float z) {
    return 1.0f / (1.0f + expf(-z));
}

__device__ __forceinline__ void gbar(unsigned* base) {
    asm volatile("s_waitcnt vmcnt(0)" ::: "memory");   // sc1 stores now visible
    __syncthreads();
    if (threadIdx.x == 0) {
        unsigned old = __hip_atomic_fetch_add(base, 1u, __ATOMIC_RELAXED,
                                              __HIP_MEMORY_SCOPE_AGENT);
        if (old == (unsigned)GRID - 1u) {
            ST1(base + 32, 1u);                        // release flag, own line
        } else {
            while (LD1(base + 32) == 0u)
                __builtin_amdgcn_s_sleep(8);
        }
        asm volatile("" ::: "memory");
    }
    __syncthreads();
}

// sampled-conv: one wave per sample, 2 samples per wave (512 waves, 1024 samples)
__device__ __forceinline__ void key_phase(const float* __restrict__ in,
                                          const float* __restrict__ sw,
                                          const float* __restrict__ sb,
                                          float* __restrict__ keyout,
                                          int mul, int dbl, int blk, int lane, int wv) {
    int g0 = blk * 4 + wv;
#pragma unroll
    for (int rep = 0; rep < 2; ++rep) {
        int s = g0 + rep * 512;
        int ii = s >> 5, jj = s & 31;
        int qy = (ii * mul) >> 5, qx = (jj * mul) >> 5;
        int by = dbl ? 2 * qy : qy - 1;
        int bx = dbl ? 2 * qx : qx - 1;
        float p0, p1, p2;
        {
            int l = lane;                    // < 64 < 75: always a valid tap index
            int ci = l / 25, rm = l % 25, r = rm / 5, cc = rm % 5;
            int y = by + r, x = bx + cc;
            float xv = 0.f;
            if ((unsigned)y < 1024u && (unsigned)x < 1024u)
                xv = 2.0f * in[ci * 1048576 + y * 1024 + x] - 1.0f;
            p0 = xv * sw[l]; p1 = xv * sw[75 + l]; p2 = xv * sw[150 + l];
        }
        if (lane < 11) {
            int l = lane + 64;
            int ci = l / 25, rm = l % 25, r = rm / 5, cc = rm % 5;
            int y = by + r, x = bx + cc;
            float xv = 0.f;
            if ((unsigned)y < 1024u && (unsigned)x < 1024u)
                xv = 2.0f * in[ci * 1048576 + y * 1024 + x] - 1.0f;
            p0 += xv * sw[l]; p1 += xv * sw[75 + l]; p2 += xv * sw[150 + l];
        }
#pragma unroll
        for (int off = 32; off > 0; off >>= 1) {
            p0 += __shfl_xor(p0, off, 64);
            p1 += __shfl_xor(p1, off, 64);
            p2 += __shfl_xor(p2, off, 64);
        }
        if (lane == 0) {
            ST1(keyout + s,        sigmoidf_(p0 + sb[0]));
            ST1(keyout + 1024 + s, sigmoidf_(p1 + sb[1]));
            ST1(keyout + 2048 + s, sigmoidf_(p2 + sb[2]));
        }
    }
}

// logits with pre-loaded keys row (kvr[12], static addresses loaded at entry)
__device__ __forceinline__ void logits_phase(const float* __restrict__ kvr,
                                             const float* __restrict__ keyvec,
                                             float* __restrict__ logit,
                                             int n, int t, int lane, int wv,
                                             float* __restrict__ sred) {
    float s = 0.f;
#pragma unroll
    for (int m = 0; m < 12; ++m) s += kvr[m] * LD1(keyvec + m * 256 + t);
#pragma unroll
    for (int off = 32; off > 0; off >>= 1) s += __shfl_xor(s, off, 64);
    if (lane == 0) sred[wv] = s;
    __syncthreads();
    if (t == 0) ST1(logit + n, sred[0] + sred[1] + sred[2] + sred[3]);
}

// softmax(logit[100]) -> satt (uncached logit reads; runs in every block)
__device__ __forceinline__ void softmax_phase(const float* __restrict__ logit,
                                              float* __restrict__ satt,
                                              int lane, int wv) {
    if (wv == 0) {
        float v1 = LD1(logit + lane);
        float v2 = (lane + 64 < 100) ? LD1(logit + lane + 64) : -3.4e38f;
        float mx = fmaxf(v1, v2);
#pragma unroll
        for (int off = 32; off > 0; off >>= 1) mx = fmaxf(mx, __shfl_xor(mx, off, 64));
        float e1 = expf(v1 - mx);
        float e2 = (lane + 64 < 100) ? expf(v2 - mx) : 0.f;
        float s = e1 + e2;
#pragma unroll
        for (int off = 32; off > 0; off >>= 1) s += __shfl_xor(s, off, 64);
        float inv = 1.0f / s;
        satt[lane] = e1 * inv;
        if (lane + 64 < 100) satt[lane + 64] = e2 * inv;
    }
    __syncthreads();
}

__global__ __launch_bounds__(256, 1) void k_fused(
    const float* __restrict__ in, const float* __restrict__ cw,
    const float* __restrict__ cb, const float* __restrict__ keys,
    const float* __restrict__ vals, float* __restrict__ out,
    float* __restrict__ ws, unsigned* __restrict__ ctr)
{
    __shared__ float smem[2624];
    float* sk1  = smem;          // 225  kern1 (persists C->F)
    float* sk2  = smem + 232;    // 225  kern2
    float* satt = smem + 464;    // 100  softmax
    float* sred = smem + 576;    // 4    cross-wave reduce
    float* sw   = smem + 592;    // 225  conv weights, then w_eff
    float* sb   = smem + 824;    // 3    bias
    float* sW   = smem + 832;    // 1521 composite W [(ci*3+o)*169 + e*13+f]
    float* sWy  = smem + 2356;   // 117
    float* sWx  = smem + 2480;   // 117
    float* sWxy = smem + 2600;   // 9

    float* key1   = ws;          // 3072
    float* logit1 = ws + 3072;   // 100
    float* key2   = ws + 3200;   // 3072
    float* logit2 = ws + 6400;   // 100

    const int t = threadIdx.x, lane = t & 63, wv = t >> 6;
    const int blk = blockIdx.x;

    // static prefetch: this block's keys row (coalesced, shared by B and E)
    float kvr[12];
    if (blk < 100) {
        const float* kr = keys + blk * 3072;
#pragma unroll
        for (int m = 0; m < 12; ++m) kvr[m] = kr[m * 256 + t];
    } else {
#pragma unroll
        for (int m = 0; m < 12; ++m) kvr[m] = 0.f;
    }

    if (t < 225) sw[t] = cw[t];
    if (t < 3)   sb[t] = cb[t];
    __syncthreads();

    // ---- A: key1 (distributed) ----
    key_phase(in, sw, sb, key1, 510, 1, blk, lane, wv);
    gbar(ctr + 0 * 512);

    // ---- B: logit1 (blocks 0..99) ----
    if (blk < 100) logits_phase(kvr, key1, logit1, blk, t, lane, wv, sred);
    gbar(ctr + 1 * 512);

    // ---- C (replicated): softmax + kern1 -> LDS, w_eff -> LDS ----
    softmax_phase(logit1, satt, lane, wv);
    if (t < 225) {
        float s = 0.f;
#pragma clang loop unroll(disable)
        for (int n = 0; n < 100; ++n) s += vals[n * 225 + t] * satt[n];
        sk1[t] = s;
    }
    __syncthreads();
    if (t < 225) {   // w_eff[co][ci][a][bb] = conv(convT(.,kern1)) composite
        int co = t / 75, rem = t % 75, ci = rem / 25, a = (rem % 25) / 5, bb = rem % 5;
        float s = 0.f;
#pragma clang loop unroll(disable)
        for (int c = 0; c < 5; ++c) {
            int u = c + 2 * a - 4;
            if ((unsigned)u >= 5u) continue;
#pragma clang loop unroll(disable)
            for (int d = 0; d < 5; ++d) {
                int v = d + 2 * bb - 4;
                if ((unsigned)v >= 5u) continue;
                for (int cm = 0; cm < 3; ++cm)
                    s += sk1[ci * 75 + cm * 25 + c * 5 + d] * cw[co * 75 + cm * 25 + u * 5 + v];
            }
        }
        sw[t] = s;    // nobody reads old sw in this phase
    }
    __syncthreads();

    // ---- D: key2 via w_eff (distributed) ----
    key_phase(in, sw, sb, key2, 1022, 0, blk, lane, wv);
    gbar(ctr + 2 * 512);

    // ---- E: logit2 (blocks 0..99) ----
    if (blk < 100) logits_phase(kvr, key2, logit2, blk, t, lane, wv, sred);
    gbar(ctr + 3 * 512);

    // ---- F (replicated): softmax + kern2 -> LDS, composite tables (ROLLED) ----
    softmax_phase(logit2, satt, lane, wv);
    if (t < 225) {
        float s = 0.f;
#pragma clang loop unroll(disable)
        for (int n = 0; n < 100; ++n) s += vals[n * 225 + t] * satt[n];
        sk2[t] = s;
    }
    __syncthreads();
#pragma clang loop unroll(disable)
    for (int idx = t; idx < 1521; idx += 256) {   // W
        int ci = idx / 507, rem = idx % 507, o = rem / 169;
        int ef = rem % 169, e = ef / 13, f = ef % 13;
        float s = 0.f;
#pragma clang loop unroll(disable)
        for (int c = 0; c < 5; ++c) {
            int a = e - 2 * c;
            if ((unsigned)a >= 5u) continue;
#pragma clang loop unroll(disable)
            for (int d = 0; d < 5; ++d) {
                int b2 = f - 2 * d;
                if ((unsigned)b2 >= 5u) continue;
                for (int cm = 0; cm < 3; ++cm)
                    s += sk1[ci * 75 + cm * 25 + c * 5 + d] * sk2[cm * 75 + o * 25 + a * 5 + b2];
            }
        }
        sW[idx] = s;
    }
    if (t < 117) {   // Wy: phantom out1-row (c=1 -> oy1=-1), a=4
        int ci = t / 39, o = (t % 39) / 13, f = t % 13;
        float s = 0.f;
#pragma clang loop unroll(disable)
        for (int d = 0; d < 5; ++d) {
            int b2 = f - 2 * d;
            if ((unsigned)b2 >= 5u) continue;
            for (int cm = 0; cm < 3; ++cm)
                s += sk1[ci * 75 + cm * 25 + 5 + d] * sk2[cm * 75 + o * 25 + 20 + b2];
        }
        sWy[(ci * 3 + o) * 13 + f] = s;
    }
    if (t >= 128 && t < 245) {   // Wx: phantom out1-col (d=1 -> ox1=-1), b=4
        int q = t - 128;
        int ci = q / 39, o = (q % 39) / 13, e = q % 13;
        float s = 0.f;
#pragma clang loop unroll(disable)
        for (int c = 0; c < 5; ++c) {
            int a = e - 2 * c;
            if ((unsigned)a >= 5u) continue;
            for (int cm = 0; cm < 3; ++cm)
                s += sk1[ci * 75 + cm * 25 + c * 5 + 1] * sk2[cm * 75 + o * 25 + a * 5 + 4];
        }
        sWx[(ci * 3 + o) * 13 + e] = s;
    }
    if (t >= 246 && t < 255) {   // Wxy overlap
        int q = t - 246;
        int ci = q / 3, o = q % 3;
        float s = 0.f;
        for (int cm = 0; cm < 3; ++cm)
            s += sk1[ci * 75 + cm * 25 + 5 + 1] * sk2[cm * 75 + o * 25 + 20 + 4];
        sWxy[ci * 3 + o] = s;
    }
    __syncthreads();

    // ---- G: final sampled composite convT + sigmoid (tables in LDS) ----
    if (t < 128) {
        int i = blk, j = t;
        int R = (i * 4093) >> 7;
        int C = (j * 4093) >> 7;
        int ybase = (R + 6) >> 2, r0 = (R + 6) & 3, nk = (r0 == 0) ? 4 : 3;
        int xbase = (C + 6) >> 2, f0 = (C + 6) & 3, nl = (f0 == 0) ? 4 : 3;
        float a0 = 0.f, a1 = 0.f, a2 = 0.f;
        for (int k = 0; k < nk; ++k) {
            int iy = ybase - k;
            if ((unsigned)iy >= 1024u) continue;
            int e = r0 + 4 * k;
            for (int l = 0; l < nl; ++l) {
                int ix = xbase - l;
                if ((unsigned)ix >= 1024u) continue;
                int f = f0 + 4 * l;
                int off = iy * 1024 + ix;
                float x0 = 2.0f * in[off] - 1.0f;
                float x1 = 2.0f * in[1048576 + off] - 1.0f;
                float x2 = 2.0f * in[2097152 + off] - 1.0f;
                int wi = e * 13 + f;
                a0 += x0 * sW[wi]           + x1 * sW[3 * 169 + wi] + x2 * sW[6 * 169 + wi];
                a1 += x0 * sW[169 + wi]     + x1 * sW[4 * 169 + wi] + x2 * sW[7 * 169 + wi];
                a2 += x0 * sW[2 * 169 + wi] + x1 * sW[5 * 169 + wi] + x2 * sW[8 * 169 + wi];
            }
        }
        if (R == 0) {
            for (int l = 0; l < nl; ++l) {
                int ix = xbase - l;
                if ((unsigned)ix >= 1024u) continue;
                int f = f0 + 4 * l;
                float x0 = 2.0f * in[ix] - 1.0f;
                float x1 = 2.0f * in[1048576 + ix] - 1.0f;
                float x2 = 2.0f * in[2097152 + ix] - 1.0f;
                a0 -= x0 * sWy[f]          + x1 * sWy[3 * 13 + f] + x2 * sWy[6 * 13 + f];
                a1 -= x0 * sWy[13 + f]     + x1 * sWy[4 * 13 + f] + x2 * sWy[7 * 13 + f];
                a2 -= x0 * sWy[2 * 13 + f] + x1 * sWy[5 * 13 + f] + x2 * sWy[8 * 13 + f];
            }
        }
        if (C == 0) {
            for (int k = 0; k < nk; ++k) {
                int iy = ybase - k;
                if ((unsigned)iy >= 1024u) continue;
                int e = r0 + 4 * k;
                int off = iy * 1024;
                float x0 = 2.0f * in[off] - 1.0f;
                float x1 = 2.0f * in[1048576 + off] - 1.0f;
                float x2 = 2.0f * in[2097152 + off] - 1.0f;
                a0 -= x0 * sWx[e]          + x1 * sWx[3 * 13 + e] + x2 * sWx[6 * 13 + e];
                a1 -= x0 * sWx[13 + e]     + x1 * sWx[4 * 13 + e] + x2 * sWx[7 * 13 + e];
                a2 -= x0 * sWx[2 * 13 + e] + x1 * sWx[5 * 13 + e] + x2 * sWx[8 * 13 + e];
            }
        }
        if (R == 0 && C == 0) {
            float x0 = 2.0f * in[0] - 1.0f;
            float x1 = 2.0f * in[1048576] - 1.0f;
            float x2 = 2.0f * in[2097152] - 1.0f;
            a0 += x0 * sWxy[0] + x1 * sWxy[3] + x2 * sWxy[6];
            a1 += x0 * sWxy[1] + x1 * sWxy[4] + x2 * sWxy[7];
            a2 += x0 * sWxy[2] + x1 * sWxy[5] + x2 * sWxy[8];
        }
        int T = i * 128 + j;
        out[T]             = sigmoidf_(a0);
        out[16384 + T]     = sigmoidf_(a1);
        out[2 * 16384 + T] = sigmoidf_(a2);
    }
}

extern "C" void kernel_launch(void* const* d_in, const int* in_sizes, int n_in,
                              void* d_out, int out_size, void* d_ws, size_t ws_size,
                              hipStream_t stream) {
    const float* in   = (const float*)d_in[0];   // [3,1024,1024]
    const float* cw   = (const float*)d_in[1];   // [3,3,5,5]
    const float* cb   = (const float*)d_in[2];   // [3]
    const float* keys = (const float*)d_in[3];   // [100,3072]
    const float* vals = (const float*)d_in[4];   // [100,225]
    float* out = (float*)d_out;                  // [3,128,128] fp32

    unsigned* ctr = (unsigned*)d_ws;             // 4 barriers x 2KB
    float* wsf = (float*)((char*)d_ws + 8192);   // float scratch region

    hipMemsetAsync(d_ws, 0, 8192, stream);       // zero barrier state
    k_fused<<<GRID, 256, 0, stream>>>(in, cw, cb, keys, vals, out, wsf, ctr);
}

// Round 12
// 116.408 us; speedup vs baseline: 1.2831x; 1.2831x over previous
//
#include <hip/hip_runtime.h>
#include <hip/hip_bf16.h>

// Single persistent kernel, 4 barriers (measured-best structure: R6/R9 = 49us
// kernel, dur 118). R12 isolated change: ENTRY PREFETCH of all static loads
// (stage-1/2 conv taps -> 16 regs, block's keys row -> 12 regs), everything
// fully unrolled (R11: rolling the vals loop serialized its global loads,
// +34us -- unroll == memory pipelining).
// Structure (validated R1-R11): looper == sigmoid(3.0) exactly -> exactly two
// long_conv applications; lc_* inputs unused. Phases:
//   A: key1[3][1024] = sigmoid(sampled stride-2 conv of 2x-1)  [distributed]
//   bar1
//   B: logit1[100] = keys @ key1, one block per row (keys row in regs)
//   bar2
//   C: softmax -> kern1 (LDS) -> w_eff (LDS)            [REPLICATED, all blocks]
//   D: key2 via w_eff (composite conv(convT(.,kern1)))          [distributed]
//   bar3
//   E: logit2[100]
//   bar4
//   F: softmax -> kern2 (LDS) -> composite stride-4 13x13 convT weights
//      W/Wy/Wx/Wxy in LDS                               [REPLICATED, all blocks]
//   G: out = sigmoid(composite convT at (i*4093/128, j*4093/128))
// Ledger (measured): agent acquire/release fences forbidden (buffer_inv/wbl2,
// R4); cross-block data sc1 relaxed-agent only; barrier mechanics irrelevant
// (R9); barrier count irrelevant (R7/R10); no dynamic-indexed register arrays
// (R7 spill); no rolled global-load loops (R11).
// Deadlock safety: 128 blocks x 256 thr, launch_bounds(256,1), 10.5KB LDS.

#define GRID 128

#define LD1(p)     __hip_atomic_load((p), __ATOMIC_RELAXED, __HIP_MEMORY_SCOPE_AGENT)
#define ST1(p, v)  __hip_atomic_store((p), (v), __ATOMIC_RELAXED, __HIP_MEMORY_SCOPE_AGENT)

__device__ __forceinline__ float sigmoidf_(float z) {
    return 1.0f / (1.0f + expf(-z));
}

__device__ __forceinline__ void gbar(unsigned* base) {
    asm volatile("s_waitcnt vmcnt(0)" ::: "memory");   // sc1 stores now visible
    __syncthreads();
    if (threadIdx.x == 0) {
        unsigned old = __hip_atomic_fetch_add(base, 1u, __ATOMIC_RELAXED,
                                              __HIP_MEMORY_SCOPE_AGENT);
        if (old == (unsigned)GRID - 1u) {
            ST1(base + 32, 1u);                        // release flag, own line
        } else {
            while (LD1(base + 32) == 0u)
                __builtin_amdgcn_s_sleep(8);
        }
        asm volatile("" ::: "memory");
    }
    __syncthreads();
}

// entry tap loads for one key stage (2 samples/wave; sample = blk*4+wv+rep*512)
__device__ __forceinline__ void key_prefetch(const float* __restrict__ in,
                                             int mul, int dbl, int blk,
                                             int lane, int wv,
                                             float xa[2], float xb[2]) {
#pragma unroll
    for (int rep = 0; rep < 2; ++rep) {
        int s = blk * 4 + wv + rep * 512;
        int ii = s >> 5, jj = s & 31;
        int qy = (ii * mul) >> 5, qx = (jj * mul) >> 5;
        int by = dbl ? 2 * qy : qy - 1;
        int bx = dbl ? 2 * qx : qx - 1;
        {
            int l = lane;                    // < 64 < 75: always a valid tap
            int ci = l / 25, rm = l % 25, r = rm / 5, cc = rm % 5;
            int y = by + r, x = bx + cc;
            xa[rep] = ((unsigned)y < 1024u && (unsigned)x < 1024u)
                      ? 2.0f * in[ci * 1048576 + y * 1024 + x] - 1.0f : 0.f;
        }
        xb[rep] = 0.f;
        if (lane < 11) {
            int l = lane + 64;
            int ci = l / 25, rm = l % 25, r = rm / 5, cc = rm % 5;
            int y = by + r, x = bx + cc;
            xb[rep] = ((unsigned)y < 1024u && (unsigned)x < 1024u)
                      ? 2.0f * in[ci * 1048576 + y * 1024 + x] - 1.0f : 0.f;
        }
    }
}

// key values from prefetched taps -> key[3][1024] via sc1 stores
__device__ __forceinline__ void key_phase(const float* __restrict__ sw,
                                          const float* __restrict__ sb,
                                          const float xa[2], const float xb[2],
                                          float* __restrict__ keyout,
                                          int blk, int lane, int wv) {
#pragma unroll
    for (int rep = 0; rep < 2; ++rep) {
        int s = blk * 4 + wv + rep * 512;
        float p0 = xa[rep] * sw[lane];
        float p1 = xa[rep] * sw[75 + lane];
        float p2 = xa[rep] * sw[150 + lane];
        if (lane < 11) {
            p0 += xb[rep] * sw[64 + lane];
            p1 += xb[rep] * sw[139 + lane];
            p2 += xb[rep] * sw[214 + lane];
        }
#pragma unroll
        for (int off = 32; off > 0; off >>= 1) {
            p0 += __shfl_xor(p0, off, 64);
            p1 += __shfl_xor(p1, off, 64);
            p2 += __shfl_xor(p2, off, 64);
        }
        if (lane == 0) {
            ST1(keyout + s,        sigmoidf_(p0 + sb[0]));
            ST1(keyout + 1024 + s, sigmoidf_(p1 + sb[1]));
            ST1(keyout + 2048 + s, sigmoidf_(p2 + sb[2]));
        }
    }
}

// logits with pre-loaded keys row (kvr[12], loaded at entry)
__device__ __forceinline__ void logits_phase(const float kvr[12],
                                             const float* __restrict__ keyvec,
                                             float* __restrict__ logit,
                                             int n, int t, int lane, int wv,
                                             float* __restrict__ sred) {
    float s = 0.f;
#pragma unroll
    for (int m = 0; m < 12; ++m) s += kvr[m] * LD1(keyvec + m * 256 + t);
#pragma unroll
    for (int off = 32; off > 0; off >>= 1) s += __shfl_xor(s, off, 64);
    if (lane == 0) sred[wv] = s;
    __syncthreads();
    if (t == 0) ST1(logit + n, sred[0] + sred[1] + sred[2] + sred[3]);
}

// softmax(logit[100]) -> satt (uncached logit reads; runs in every block)
__device__ __forceinline__ void softmax_phase(const float* __restrict__ logit,
                                              float* __restrict__ satt,
                                              int lane, int wv) {
    if (wv == 0) {
        float v1 = LD1(logit + lane);
        float v2 = (lane + 64 < 100) ? LD1(logit + lane + 64) : -3.4e38f;
        float mx = fmaxf(v1, v2);
#pragma unroll
        for (int off = 32; off > 0; off >>= 1) mx = fmaxf(mx, __shfl_xor(mx, off, 64));
        float e1 = expf(v1 - mx);
        float e2 = (lane + 64 < 100) ? expf(v2 - mx) : 0.f;
        float s = e1 + e2;
#pragma unroll
        for (int off = 32; off > 0; off >>= 1) s += __shfl_xor(s, off, 64);
        float inv = 1.0f / s;
        satt[lane] = e1 * inv;
        if (lane + 64 < 100) satt[lane + 64] = e2 * inv;
    }
    __syncthreads();
}

__global__ __launch_bounds__(256, 1) void k_fused(
    const float* __restrict__ in, const float* __restrict__ cw,
    const float* __restrict__ cb, const float* __restrict__ keys,
    const float* __restrict__ vals, float* __restrict__ out,
    float* __restrict__ ws, unsigned* __restrict__ ctr)
{
    __shared__ float smem[2624];
    float* sk1  = smem;          // 225  kern1 (persists C->F)
    float* sk2  = smem + 232;    // 225  kern2
    float* satt = smem + 464;    // 100  softmax
    float* sred = smem + 576;    // 4    cross-wave reduce
    float* sw   = smem + 592;    // 225  conv weights, then w_eff
    float* sb   = smem + 824;    // 3    bias
    float* sW   = smem + 832;    // 1521 composite W [(ci*3+o)*169 + e*13+f]
    float* sWy  = smem + 2356;   // 117
    float* sWx  = smem + 2480;   // 117
    float* sWxy = smem + 2600;   // 9

    float* key1   = ws;          // 3072
    float* logit1 = ws + 3072;   // 100
    float* key2   = ws + 3200;   // 3072
    float* logit2 = ws + 6400;   // 100

    const int t = threadIdx.x, lane = t & 63, wv = t >> 6;
    const int blk = blockIdx.x;

    // ---- entry prefetch: both stages' taps + this block's keys row ----
    float xa1[2], xb1[2], xa2[2], xb2[2];
    key_prefetch(in, 510, 1, blk, lane, wv, xa1, xb1);
    key_prefetch(in, 1022, 0, blk, lane, wv, xa2, xb2);
    float kvr[12];
    if (blk < 100) {
        const float* kr = keys + blk * 3072;
#pragma unroll
        for (int m = 0; m < 12; ++m) kvr[m] = kr[m * 256 + t];
    } else {
#pragma unroll
        for (int m = 0; m < 12; ++m) kvr[m] = 0.f;
    }

    if (t < 225) sw[t] = cw[t];
    if (t < 3)   sb[t] = cb[t];
    __syncthreads();

    // ---- A: key1 (distributed) ----
    key_phase(sw, sb, xa1, xb1, key1, blk, lane, wv);
    gbar(ctr + 0 * 512);

    // ---- B: logit1 (blocks 0..99) ----
    if (blk < 100) logits_phase(kvr, key1, logit1, blk, t, lane, wv, sred);
    gbar(ctr + 1 * 512);

    // ---- C (replicated): softmax + kern1 -> LDS, w_eff -> LDS ----
    softmax_phase(logit1, satt, lane, wv);
    if (t < 225) {
        float s = 0.f;
#pragma unroll
        for (int n = 0; n < 100; ++n) s += vals[n * 225 + t] * satt[n];
        sk1[t] = s;
    }
    __syncthreads();
    if (t < 225) {   // w_eff[co][ci][a][bb] = conv(convT(.,kern1)) composite
        int co = t / 75, rem = t % 75, ci = rem / 25, a = (rem % 25) / 5, bb = rem % 5;
        float s = 0.f;
#pragma unroll
        for (int c = 0; c < 5; ++c) {
            int u = c + 2 * a - 4;
            if ((unsigned)u >= 5u) continue;
#pragma unroll
            for (int d = 0; d < 5; ++d) {
                int v = d + 2 * bb - 4;
                if ((unsigned)v >= 5u) continue;
#pragma unroll
                for (int cm = 0; cm < 3; ++cm)
                    s += sk1[ci * 75 + cm * 25 + c * 5 + d] * cw[co * 75 + cm * 25 + u * 5 + v];
            }
        }
        sw[t] = s;    // nobody reads old sw in this phase
    }
    __syncthreads();

    // ---- D: key2 via w_eff (distributed) ----
    key_phase(sw, sb, xa2, xb2, key2, blk, lane, wv);
    gbar(ctr + 2 * 512);

    // ---- E: logit2 (blocks 0..99) ----
    if (blk < 100) logits_phase(kvr, key2, logit2, blk, t, lane, wv, sred);
    gbar(ctr + 3 * 512);

    // ---- F (replicated): softmax + kern2 -> LDS, composite tables -> LDS ----
    softmax_phase(logit2, satt, lane, wv);
    if (t < 225) {
        float s = 0.f;
#pragma unroll
        for (int n = 0; n < 100; ++n) s += vals[n * 225 + t] * satt[n];
        sk2[t] = s;
    }
    __syncthreads();
    for (int idx = t; idx < 1521; idx += 256) {   // W
        int ci = idx / 507, rem = idx % 507, o = rem / 169;
        int ef = rem % 169, e = ef / 13, f = ef % 13;
        float s = 0.f;
#pragma unroll
        for (int c = 0; c < 5; ++c) {
            int a = e - 2 * c;
            if ((unsigned)a >= 5u) continue;
#pragma unroll
            for (int d = 0; d < 5; ++d) {
                int b2 = f - 2 * d;
                if ((unsigned)b2 >= 5u) continue;
#pragma unroll
                for (int cm = 0; cm < 3; ++cm)
                    s += sk1[ci * 75 + cm * 25 + c * 5 + d] * sk2[cm * 75 + o * 25 + a * 5 + b2];
            }
        }
        sW[idx] = s;
    }
    if (t < 117) {   // Wy: phantom out1-row (c=1 -> oy1=-1), a=4
        int ci = t / 39, o = (t % 39) / 13, f = t % 13;
        float s = 0.f;
#pragma unroll
        for (int d = 0; d < 5; ++d) {
            int b2 = f - 2 * d;
            if ((unsigned)b2 >= 5u) continue;
#pragma unroll
            for (int cm = 0; cm < 3; ++cm)
                s += sk1[ci * 75 + cm * 25 + 5 + d] * sk2[cm * 75 + o * 25 + 20 + b2];
        }
        sWy[(ci * 3 + o) * 13 + f] = s;
    }
    if (t >= 128 && t < 245) {   // Wx: phantom out1-col (d=1 -> ox1=-1), b=4
        int q = t - 128;
        int ci = q / 39, o = (q % 39) / 13, e = q % 13;
        float s = 0.f;
#pragma unroll
        for (int c = 0; c < 5; ++c) {
            int a = e - 2 * c;
            if ((unsigned)a >= 5u) continue;
#pragma unroll
            for (int cm = 0; cm < 3; ++cm)
                s += sk1[ci * 75 + cm * 25 + c * 5 + 1] * sk2[cm * 75 + o * 25 + a * 5 + 4];
        }
        sWx[(ci * 3 + o) * 13 + e] = s;
    }
    if (t >= 246 && t < 255) {   // Wxy overlap
        int q = t - 246;
        int ci = q / 3, o = q % 3;
        float s = 0.f;
#pragma unroll
        for (int cm = 0; cm < 3; ++cm)
            s += sk1[ci * 75 + cm * 25 + 5 + 1] * sk2[cm * 75 + o * 25 + 20 + 4];
        sWxy[ci * 3 + o] = s;
    }
    __syncthreads();

    // ---- G: final sampled composite convT + sigmoid (tables in LDS) ----
    if (t < 128) {
        int i = blk, j = t;
        int R = (i * 4093) >> 7;
        int C = (j * 4093) >> 7;
        int ybase = (R + 6) >> 2, r0 = (R + 6) & 3, nk = (r0 == 0) ? 4 : 3;
        int xbase = (C + 6) >> 2, f0 = (C + 6) & 3, nl = (f0 == 0) ? 4 : 3;
        float a0 = 0.f, a1 = 0.f, a2 = 0.f;
        for (int k = 0; k < nk; ++k) {
            int iy = ybase - k;
            if ((unsigned)iy >= 1024u) continue;
            int e = r0 + 4 * k;
            for (int l = 0; l < nl; ++l) {
                int ix = xbase - l;
                if ((unsigned)ix >= 1024u) continue;
                int f = f0 + 4 * l;
                int off = iy * 1024 + ix;
                float x0 = 2.0f * in[off] - 1.0f;
                float x1 = 2.0f * in[1048576 + off] - 1.0f;
                float x2 = 2.0f * in[2097152 + off] - 1.0f;
                int wi = e * 13 + f;
                a0 += x0 * sW[wi]           + x1 * sW[3 * 169 + wi] + x2 * sW[6 * 169 + wi];
                a1 += x0 * sW[169 + wi]     + x1 * sW[4 * 169 + wi] + x2 * sW[7 * 169 + wi];
                a2 += x0 * sW[2 * 169 + wi] + x1 * sW[5 * 169 + wi] + x2 * sW[8 * 169 + wi];
            }
        }
        if (R == 0) {
            for (int l = 0; l < nl; ++l) {
                int ix = xbase - l;
                if ((unsigned)ix >= 1024u) continue;
                int f = f0 + 4 * l;
                float x0 = 2.0f * in[ix] - 1.0f;
                float x1 = 2.0f * in[1048576 + ix] - 1.0f;
                float x2 = 2.0f * in[2097152 + ix] - 1.0f;
                a0 -= x0 * sWy[f]          + x1 * sWy[3 * 13 + f] + x2 * sWy[6 * 13 + f];
                a1 -= x0 * sWy[13 + f]     + x1 * sWy[4 * 13 + f] + x2 * sWy[7 * 13 + f];
                a2 -= x0 * sWy[2 * 13 + f] + x1 * sWy[5 * 13 + f] + x2 * sWy[8 * 13 + f];
            }
        }
        if (C == 0) {
            for (int k = 0; k < nk; ++k) {
                int iy = ybase - k;
                if ((unsigned)iy >= 1024u) continue;
                int e = r0 + 4 * k;
                int off = iy * 1024;
                float x0 = 2.0f * in[off] - 1.0f;
                float x1 = 2.0f * in[1048576 + off] - 1.0f;
                float x2 = 2.0f * in[2097152 + off] - 1.0f;
                a0 -= x0 * sWx[e]          + x1 * sWx[3 * 13 + e] + x2 * sWx[6 * 13 + e];
                a1 -= x0 * sWx[13 + e]     + x1 * sWx[4 * 13 + e] + x2 * sWx[7 * 13 + e];
                a2 -= x0 * sWx[2 * 13 + e] + x1 * sWx[5 * 13 + e] + x2 * sWx[8 * 13 + e];
            }
        }
        if (R == 0 && C == 0) {
            float x0 = 2.0f * in[0] - 1.0f;
            float x1 = 2.0f * in[1048576] - 1.0f;
            float x2 = 2.0f * in[2097152] - 1.0f;
            a0 += x0 * sWxy[0] + x1 * sWxy[3] + x2 * sWxy[6];
            a1 += x0 * sWxy[1] + x1 * sWxy[4] + x2 * sWxy[7];
            a2 += x0 * sWxy[2] + x1 * sWxy[5] + x2 * sWxy[8];
        }
        int T = i * 128 + j;
        out[T]             = sigmoidf_(a0);
        out[16384 + T]     = sigmoidf_(a1);
        out[2 * 16384 + T] = sigmoidf_(a2);
    }
}

extern "C" void kernel_launch(void* const* d_in, const int* in_sizes, int n_in,
                              void* d_out, int out_size, void* d_ws, size_t ws_size,
                              hipStream_t stream) {
    const float* in   = (const float*)d_in[0];   // [3,1024,1024]
    const float* cw   = (const float*)d_in[1];   // [3,3,5,5]
    const float* cb   = (const float*)d_in[2];   // [3]
    const float* keys = (const float*)d_in[3];   // [100,3072]
    const float* vals = (const float*)d_in[4];   // [100,225]
    float* out = (float*)d_out;                  // [3,128,128] fp32

    unsigned* ctr = (unsigned*)d_ws;             // 4 barriers x 2KB
    float* wsf = (float*)((char*)d_ws + 8192);   // float scratch region

    hipMemsetAsync(d_ws, 0, 8192, stream);       // zero barrier state
    k_fused<<<GRID, 256, 0, stream>>>(in, cw, cb, keys, vals, out, wsf, ctr);
}

// Round 13
// 115.787 us; speedup vs baseline: 1.2900x; 1.0054x over previous
//
#include <hip/hip_runtime.h>
#include <hip/hip_bf16.h>

// Single persistent kernel, 4 barriers. == R12 (measured best: kernel 45.5us,
// dur 116.4) with ONE isolated change: ATOMIC-FREE grid barrier ==
// Hypothesis: agent-scope atomic RMWs serialize globally at the coherence
// point (~100-160cyc each); 128 RMWs/barrier ~= the stubborn 8.5us that was
// invariant to line-splitting (R9), sleep tuning, and fan-in (R10). New
// barrier: arrival = sc1 STORE to own word; detection = block 0's two waves
// poll the 128 words with independent per-lane relaxed loads; release = one
// flag store, polled read-only (the pattern already in use since R5).
// Structure (validated R1-R12): looper == sigmoid(3.0) exactly -> exactly two
// long_conv applications; lc_* inputs unused. Phases:
//   A: key1[3][1024] = sigmoid(sampled stride-2 conv of 2x-1)  [distributed]
//   bar1
//   B: logit1[100] = keys @ key1, one block per row (keys row in regs)
//   bar2
//   C: softmax -> kern1 (LDS) -> w_eff (LDS)            [REPLICATED, all blocks]
//   D: key2 via w_eff (composite conv(convT(.,kern1)))          [distributed]
//   bar3
//   E: logit2[100]
//   bar4
//   F: softmax -> kern2 (LDS) -> composite stride-4 13x13 convT weights
//      W/Wy/Wx/Wxy in LDS                               [REPLICATED, all blocks]
//   G: out = sigmoid(composite convT at (i*4093/128, j*4093/128))
// Ledger (measured): agent acquire/release fences forbidden (buffer_inv/wbl2,
// R4); cross-block data sc1 relaxed-agent only; sc1 store->load visibility
// validated (R8); no dynamic-indexed register arrays (R7 spill); no rolled
// global-load loops (R11: unroll == memory pipelining); entry prefetch of all
// static loads (R12 win). Deadlock safety: 128 blocks x 256 thr,
// launch_bounds(256,1), 10.5KB LDS -> trivially co-resident on 256 CUs.
// Barrier state (4 x 1KB) zeroed by captured memset node each call.

#define GRID 128

#define LD1(p)     __hip_atomic_load((p), __ATOMIC_RELAXED, __HIP_MEMORY_SCOPE_AGENT)
#define ST1(p, v)  __hip_atomic_store((p), (v), __ATOMIC_RELAXED, __HIP_MEMORY_SCOPE_AGENT)

__device__ __forceinline__ float sigmoidf_(float z) {
    return 1.0f / (1.0f + expf(-z));
}

// base: 256 words (1KB). arrival[0..127]; release flag at word 160.
// No atomics anywhere: stores + loads only.
__device__ __forceinline__ void gbar(unsigned* base, int blk, int t) {
    asm volatile("s_waitcnt vmcnt(0)" ::: "memory");   // data sc1 stores visible
    __syncthreads();
    if (t == 0) ST1(base + blk, 1u);                   // arrival store, own word
    if (blk == 0) {
        if (t < 128) {                                 // 2 waves poll 128 words
            while (LD1(base + t) == 0u)
                __builtin_amdgcn_s_sleep(8);
        }
        __syncthreads();
        if (t == 0) ST1(base + 160, 1u);               // release flag, own line
    } else {
        if (t == 0) {
            while (LD1(base + 160) == 0u)
                __builtin_amdgcn_s_sleep(8);
        }
        __syncthreads();
    }
    asm volatile("" ::: "memory");
    __syncthreads();
}

// entry tap loads for one key stage (2 samples/wave; sample = blk*4+wv+rep*512)
__device__ __forceinline__ void key_prefetch(const float* __restrict__ in,
                                             int mul, int dbl, int blk,
                                             int lane, int wv,
                                             float xa[2], float xb[2]) {
#pragma unroll
    for (int rep = 0; rep < 2; ++rep) {
        int s = blk * 4 + wv + rep * 512;
        int ii = s >> 5, jj = s & 31;
        int qy = (ii * mul) >> 5, qx = (jj * mul) >> 5;
        int by = dbl ? 2 * qy : qy - 1;
        int bx = dbl ? 2 * qx : qx - 1;
        {
            int l = lane;                    // < 64 < 75: always a valid tap
            int ci = l / 25, rm = l % 25, r = rm / 5, cc = rm % 5;
            int y = by + r, x = bx + cc;
            xa[rep] = ((unsigned)y < 1024u && (unsigned)x < 1024u)
                      ? 2.0f * in[ci * 1048576 + y * 1024 + x] - 1.0f : 0.f;
        }
        xb[rep] = 0.f;
        if (lane < 11) {
            int l = lane + 64;
            int ci = l / 25, rm = l % 25, r = rm / 5, cc = rm % 5;
            int y = by + r, x = bx + cc;
            xb[rep] = ((unsigned)y < 1024u && (unsigned)x < 1024u)
                      ? 2.0f * in[ci * 1048576 + y * 1024 + x] - 1.0f : 0.f;
        }
    }
}

// key values from prefetched taps -> key[3][1024] via sc1 stores
__device__ __forceinline__ void key_phase(const float* __restrict__ sw,
                                          const float* __restrict__ sb,
                                          const float xa[2], const float xb[2],
                                          float* __restrict__ keyout,
                                          int blk, int lane, int wv) {
#pragma unroll
    for (int rep = 0; rep < 2; ++rep) {
        int s = blk * 4 + wv + rep * 512;
        float p0 = xa[rep] * sw[lane];
        float p1 = xa[rep] * sw[75 + lane];
        float p2 = xa[rep] * sw[150 + lane];
        if (lane < 11) {
            p0 += xb[rep] * sw[64 + lane];
            p1 += xb[rep] * sw[139 + lane];
            p2 += xb[rep] * sw[214 + lane];
        }
#pragma unroll
        for (int off = 32; off > 0; off >>= 1) {
            p0 += __shfl_xor(p0, off, 64);
            p1 += __shfl_xor(p1, off, 64);
            p2 += __shfl_xor(p2, off, 64);
        }
        if (lane == 0) {
            ST1(keyout + s,        sigmoidf_(p0 + sb[0]));
            ST1(keyout + 1024 + s, sigmoidf_(p1 + sb[1]));
            ST1(keyout + 2048 + s, sigmoidf_(p2 + sb[2]));
        }
    }
}

// logits with pre-loaded keys row (kvr[12], loaded at entry)
__device__ __forceinline__ void logits_phase(const float kvr[12],
                                             const float* __restrict__ keyvec,
                                             float* __restrict__ logit,
                                             int n, int t, int lane, int wv,
                                             float* __restrict__ sred) {
    float s = 0.f;
#pragma unroll
    for (int m = 0; m < 12; ++m) s += kvr[m] * LD1(keyvec + m * 256 + t);
#pragma unroll
    for (int off = 32; off > 0; off >>= 1) s += __shfl_xor(s, off, 64);
    if (lane == 0) sred[wv] = s;
    __syncthreads();
    if (t == 0) ST1(logit + n, sred[0] + sred[1] + sred[2] + sred[3]);
}

// softmax(logit[100]) -> satt (uncached logit reads; runs in every block)
__device__ __forceinline__ void softmax_phase(const float* __restrict__ logit,
                                              float* __restrict__ satt,
                                              int lane, int wv) {
    if (wv == 0) {
        float v1 = LD1(logit + lane);
        float v2 = (lane + 64 < 100) ? LD1(logit + lane + 64) : -3.4e38f;
        float mx = fmaxf(v1, v2);
#pragma unroll
        for (int off = 32; off > 0; off >>= 1) mx = fmaxf(mx, __shfl_xor(mx, off, 64));
        float e1 = expf(v1 - mx);
        float e2 = (lane + 64 < 100) ? expf(v2 - mx) : 0.f;
        float s = e1 + e2;
#pragma unroll
        for (int off = 32; off > 0; off >>= 1) s += __shfl_xor(s, off, 64);
        float inv = 1.0f / s;
        satt[lane] = e1 * inv;
        if (lane + 64 < 100) satt[lane + 64] = e2 * inv;
    }
    __syncthreads();
}

__global__ __launch_bounds__(256, 1) void k_fused(
    const float* __restrict__ in, const float* __restrict__ cw,
    const float* __restrict__ cb, const float* __restrict__ keys,
    const float* __restrict__ vals, float* __restrict__ out,
    float* __restrict__ ws, unsigned* __restrict__ ctr)
{
    __shared__ float smem[2624];
    float* sk1  = smem;          // 225  kern1 (persists C->F)
    float* sk2  = smem + 232;    // 225  kern2
    float* satt = smem + 464;    // 100  softmax
    float* sred = smem + 576;    // 4    cross-wave reduce
    float* sw   = smem + 592;    // 225  conv weights, then w_eff
    float* sb   = smem + 824;    // 3    bias
    float* sW   = smem + 832;    // 1521 composite W [(ci*3+o)*169 + e*13+f]
    float* sWy  = smem + 2356;   // 117
    float* sWx  = smem + 2480;   // 117
    float* sWxy = smem + 2600;   // 9

    float* key1   = ws;          // 3072
    float* logit1 = ws + 3072;   // 100
    float* key2   = ws + 3200;   // 3072
    float* logit2 = ws + 6400;   // 100

    const int t = threadIdx.x, lane = t & 63, wv = t >> 6;
    const int blk = blockIdx.x;

    // ---- entry prefetch: both stages' taps + this block's keys row ----
    float xa1[2], xb1[2], xa2[2], xb2[2];
    key_prefetch(in, 510, 1, blk, lane, wv, xa1, xb1);
    key_prefetch(in, 1022, 0, blk, lane, wv, xa2, xb2);
    float kvr[12];
    if (blk < 100) {
        const float* kr = keys + blk * 3072;
#pragma unroll
        for (int m = 0; m < 12; ++m) kvr[m] = kr[m * 256 + t];
    } else {
#pragma unroll
        for (int m = 0; m < 12; ++m) kvr[m] = 0.f;
    }

    if (t < 225) sw[t] = cw[t];
    if (t < 3)   sb[t] = cb[t];
    __syncthreads();

    // ---- A: key1 (distributed) ----
    key_phase(sw, sb, xa1, xb1, key1, blk, lane, wv);
    gbar(ctr + 0 * 256, blk, t);

    // ---- B: logit1 (blocks 0..99) ----
    if (blk < 100) logits_phase(kvr, key1, logit1, blk, t, lane, wv, sred);
    gbar(ctr + 1 * 256, blk, t);

    // ---- C (replicated): softmax + kern1 -> LDS, w_eff -> LDS ----
    softmax_phase(logit1, satt, lane, wv);
    if (t < 225) {
        float s = 0.f;
#pragma unroll
        for (int n = 0; n < 100; ++n) s += vals[n * 225 + t] * satt[n];
        sk1[t] = s;
    }
    __syncthreads();
    if (t < 225) {   // w_eff[co][ci][a][bb] = conv(convT(.,kern1)) composite
        int co = t / 75, rem = t % 75, ci = rem / 25, a = (rem % 25) / 5, bb = rem % 5;
        float s = 0.f;
#pragma unroll
        for (int c = 0; c < 5; ++c) {
            int u = c + 2 * a - 4;
            if ((unsigned)u >= 5u) continue;
#pragma unroll
            for (int d = 0; d < 5; ++d) {
                int v = d + 2 * bb - 4;
                if ((unsigned)v >= 5u) continue;
#pragma unroll
                for (int cm = 0; cm < 3; ++cm)
                    s += sk1[ci * 75 + cm * 25 + c * 5 + d] * cw[co * 75 + cm * 25 + u * 5 + v];
            }
        }
        sw[t] = s;    // nobody reads old sw in this phase
    }
    __syncthreads();

    // ---- D: key2 via w_eff (distributed) ----
    key_phase(sw, sb, xa2, xb2, key2, blk, lane, wv);
    gbar(ctr + 2 * 256, blk, t);

    // ---- E: logit2 (blocks 0..99) ----
    if (blk < 100) logits_phase(kvr, key2, logit2, blk, t, lane, wv, sred);
    gbar(ctr + 3 * 256, blk, t);

    // ---- F (replicated): softmax + kern2 -> LDS, composite tables -> LDS ----
    softmax_phase(logit2, satt, lane, wv);
    if (t < 225) {
        float s = 0.f;
#pragma unroll
        for (int n = 0; n < 100; ++n) s += vals[n * 225 + t] * satt[n];
        sk2[t] = s;
    }
    __syncthreads();
    for (int idx = t; idx < 1521; idx += 256) {   // W
        int ci = idx / 507, rem = idx % 507, o = rem / 169;
        int ef = rem % 169, e = ef / 13, f = ef % 13;
        float s = 0.f;
#pragma unroll
        for (int c = 0; c < 5; ++c) {
            int a = e - 2 * c;
            if ((unsigned)a >= 5u) continue;
#pragma unroll
            for (int d = 0; d < 5; ++d) {
                int b2 = f - 2 * d;
                if ((unsigned)b2 >= 5u) continue;
#pragma unroll
                for (int cm = 0; cm < 3; ++cm)
                    s += sk1[ci * 75 + cm * 25 + c * 5 + d] * sk2[cm * 75 + o * 25 + a * 5 + b2];
            }
        }
        sW[idx] = s;
    }
    if (t < 117) {   // Wy: phantom out1-row (c=1 -> oy1=-1), a=4
        int ci = t / 39, o = (t % 39) / 13, f = t % 13;
        float s = 0.f;
#pragma unroll
        for (int d = 0; d < 5; ++d) {
            int b2 = f - 2 * d;
            if ((unsigned)b2 >= 5u) continue;
#pragma unroll
            for (int cm = 0; cm < 3; ++cm)
                s += sk1[ci * 75 + cm * 25 + 5 + d] * sk2[cm * 75 + o * 25 + 20 + b2];
        }
        sWy[(ci * 3 + o) * 13 + f] = s;
    }
    if (t >= 128 && t < 245) {   // Wx: phantom out1-col (d=1 -> ox1=-1), b=4
        int q = t - 128;
        int ci = q / 39, o = (q % 39) / 13, e = q % 13;
        float s = 0.f;
#pragma unroll
        for (int c = 0; c < 5; ++c) {
            int a = e - 2 * c;
            if ((unsigned)a >= 5u) continue;
#pragma unroll
            for (int cm = 0; cm < 3; ++cm)
                s += sk1[ci * 75 + cm * 25 + c * 5 + 1] * sk2[cm * 75 + o * 25 + a * 5 + 4];
        }
        sWx[(ci * 3 + o) * 13 + e] = s;
    }
    if (t >= 246 && t < 255) {   // Wxy overlap
        int q = t - 246;
        int ci = q / 3, o = q % 3;
        float s = 0.f;
#pragma unroll
        for (int cm = 0; cm < 3; ++cm)
            s += sk1[ci * 75 + cm * 25 + 5 + 1] * sk2[cm * 75 + o * 25 + 20 + 4];
        sWxy[ci * 3 + o] = s;
    }
    __syncthreads();

    // ---- G: final sampled composite convT + sigmoid (tables in LDS) ----
    if (t < 128) {
        int i = blk, j = t;
        int R = (i * 4093) >> 7;
        int C = (j * 4093) >> 7;
        int ybase = (R + 6) >> 2, r0 = (R + 6) & 3, nk = (r0 == 0) ? 4 : 3;
        int xbase = (C + 6) >> 2, f0 = (C + 6) & 3, nl = (f0 == 0) ? 4 : 3;
        float a0 = 0.f, a1 = 0.f, a2 = 0.f;
        for (int k = 0; k < nk; ++k) {
            int iy = ybase - k;
            if ((unsigned)iy >= 1024u) continue;
            int e = r0 + 4 * k;
            for (int l = 0; l < nl; ++l) {
                int ix = xbase - l;
                if ((unsigned)ix >= 1024u) continue;
                int f = f0 + 4 * l;
                int off = iy * 1024 + ix;
                float x0 = 2.0f * in[off] - 1.0f;
                float x1 = 2.0f * in[1048576 + off] - 1.0f;
                float x2 = 2.0f * in[2097152 + off] - 1.0f;
                int wi = e * 13 + f;
                a0 += x0 * sW[wi]           + x1 * sW[3 * 169 + wi] + x2 * sW[6 * 169 + wi];
                a1 += x0 * sW[169 + wi]     + x1 * sW[4 * 169 + wi] + x2 * sW[7 * 169 + wi];
                a2 += x0 * sW[2 * 169 + wi] + x1 * sW[5 * 169 + wi] + x2 * sW[8 * 169 + wi];
            }
        }
        if (R == 0) {
            for (int l = 0; l < nl; ++l) {
                int ix = xbase - l;
                if ((unsigned)ix >= 1024u) continue;
                int f = f0 + 4 * l;
                float x0 = 2.0f * in[ix] - 1.0f;
                float x1 = 2.0f * in[1048576 + ix] - 1.0f;
                float x2 = 2.0f * in[2097152 + ix] - 1.0f;
                a0 -= x0 * sWy[f]          + x1 * sWy[3 * 13 + f] + x2 * sWy[6 * 13 + f];
                a1 -= x0 * sWy[13 + f]     + x1 * sWy[4 * 13 + f] + x2 * sWy[7 * 13 + f];
                a2 -= x0 * sWy[2 * 13 + f] + x1 * sWy[5 * 13 + f] + x2 * sWy[8 * 13 + f];
            }
        }
        if (C == 0) {
            for (int k = 0; k < nk; ++k) {
                int iy = ybase - k;
                if ((unsigned)iy >= 1024u) continue;
                int e = r0 + 4 * k;
                int off = iy * 1024;
                float x0 = 2.0f * in[off] - 1.0f;
                float x1 = 2.0f * in[1048576 + off] - 1.0f;
                float x2 = 2.0f * in[2097152 + off] - 1.0f;
                a0 -= x0 * sWx[e]          + x1 * sWx[3 * 13 + e] + x2 * sWx[6 * 13 + e];
                a1 -= x0 * sWx[13 + e]     + x1 * sWx[4 * 13 + e] + x2 * sWx[7 * 13 + e];
                a2 -= x0 * sWx[2 * 13 + e] + x1 * sWx[5 * 13 + e] + x2 * sWx[8 * 13 + e];
            }
        }
        if (R == 0 && C == 0) {
            float x0 = 2.0f * in[0] - 1.0f;
            float x1 = 2.0f * in[1048576] - 1.0f;
            float x2 = 2.0f * in[2097152] - 1.0f;
            a0 += x0 * sWxy[0] + x1 * sWxy[3] + x2 * sWxy[6];
            a1 += x0 * sWxy[1] + x1 * sWxy[4] + x2 * sWxy[7];
            a2 += x0 * sWxy[2] + x1 * sWxy[5] + x2 * sWxy[8];
        }
        int T = i * 128 + j;
        out[T]             = sigmoidf_(a0);
        out[16384 + T]     = sigmoidf_(a1);
        out[2 * 16384 + T] = sigmoidf_(a2);
    }
}

extern "C" void kernel_launch(void* const* d_in, const int* in_sizes, int n_in,
                              void* d_out, int out_size, void* d_ws, size_t ws_size,
                              hipStream_t stream) {
    const float* in   = (const float*)d_in[0];   // [3,1024,1024]
    const float* cw   = (const float*)d_in[1];   // [3,3,5,5]
    const float* cb   = (const float*)d_in[2];   // [3]
    const float* keys = (const float*)d_in[3];   // [100,3072]
    const float* vals = (const float*)d_in[4];   // [100,225]
    float* out = (float*)d_out;                  // [3,128,128] fp32

    unsigned* ctr = (unsigned*)d_ws;             // 4 barriers x 1KB (store-based)
    float* wsf = (float*)((char*)d_ws + 8192);   // float scratch region

    hipMemsetAsync(d_ws, 0, 4096, stream);       // zero barrier state
    k_fused<<<GRID, 256, 0, stream>>>(in, cw, cb, keys, vals, out, wsf, ctr);
}